// Round 1
// baseline (136.467 us; speedup 1.0000x reference)
//
#include <hip/hip_runtime.h>

typedef unsigned short u16;
typedef __attribute__((ext_vector_type(8))) short bf16x8;
typedef __attribute__((ext_vector_type(4))) float f32x4;

#define NJ 4094

__device__ __forceinline__ u16 f2bf(float f) {
  union { float f; unsigned u; } v;
  v.f = f;
  unsigned r = v.u + 0x7fffu + ((v.u >> 16) & 1u);
  return (u16)(r >> 16);
}

// ---------------- out = x1 (residual init; x4 atomically added later) ----------------
__global__ __launch_bounds__(256) void init_out_kernel(const float4* __restrict__ x,
                                                       float4* __restrict__ out) {
  int i = blockIdx.x * 256 + threadIdx.x;
  out[i] = x[i];
}

// ---------------- dilated conv1d -> x2 in bf16, two layouts, zero-padded to 4096 ----------------
// x2[b,c,j] = bias[c] + sum_i w[c,i,0]*x(j-1) + w[c,i,1]*x(j+1) + w[c,i,2]*x(j+3), OOB x = 0
__global__ __launch_bounds__(256) void conv_kernel(
    const float* __restrict__ x, const float* __restrict__ w,
    const float* __restrict__ bias, u16* __restrict__ x2n, u16* __restrict__ x2T) {
  __shared__ float xs[64 * 68];       // [in_ch][68 window]
  __shared__ float wl[64 * 64 * 3];   // [in_ch][out_ch][tap]
  const int b = blockIdx.x >> 6, jt = blockIdx.x & 63;
  const int t = threadIdx.x;
  for (int idx = t; idx < 64 * 68; idx += 256) {
    int i = idx / 68, p = idx - i * 68;
    int jg = jt * 64 - 1 + p;          // window starts at j-1
    float v = 0.f;
    if (jg >= 0 && jg < 4096) v = x[(b * 64 + i) * 4096 + jg];
    xs[idx] = v;
  }
  for (int idx = t; idx < 64 * 64 * 3; idx += 256) {
    int tap = idx % 3, ci = idx / 3;
    int c = ci >> 6, i = ci & 63;      // source w[c][i][tap], coalesced read
    wl[(i * 64 + c) * 3 + tap] = w[idx];
  }
  __syncthreads();
  const int c = t & 63, jsub = t >> 6;
  float acc[16];
  float bv = bias[c];
#pragma unroll
  for (int k = 0; k < 16; k++) acc[k] = bv;
  for (int i = 0; i < 64; i++) {
    float w0 = wl[(i * 64 + c) * 3 + 0];
    float w1 = wl[(i * 64 + c) * 3 + 1];
    float w2 = wl[(i * 64 + c) * 3 + 2];
    const float* xr = &xs[i * 68 + jsub * 16];
#pragma unroll
    for (int k = 0; k < 16; k++)
      acc[k] += w0 * xr[k] + w1 * xr[k + 2] + w2 * xr[k + 4];
  }
#pragma unroll
  for (int k = 0; k < 16; k++) {
    int jg = jt * 64 + jsub * 16 + k;
    float v = (jg < NJ) ? acc[k] : 0.f;   // zero-pad j=4094,4095
    u16 hv = f2bf(v);
    x2n[(b * 64 + c) * 4096 + jg] = hv;   // [b][c][j]
    x2T[(b * 4096 + jg) * 64 + c] = hv;   // [b][j][c]
  }
}

// ---------------- fused: S = X1^T X2 (both batches) -> sigmoid -> x4 += X2 P^T ----------------
// grid (64 i-blocks, 8 j-chunks), 256 thr = 4 waves. Each block: 64-i strip, 8 j-tiles of 64.
// MFMA 16x16x32 bf16 layouts (gfx950, HW-verified):
//   A: lane holds A[m=lane&15][k=(lane>>4)*8 + r], r=0..7
//   B: lane holds B[k=(lane>>4)*8 + r][n=lane&15]
//   C/D: lane,reg r holds D[(lane>>4)*4 + r][lane&15]
__global__ __launch_bounds__(256, 2) void fused_kernel(
    const float* __restrict__ x, const u16* __restrict__ x2n_g,
    const u16* __restrict__ x2T_g, float* __restrict__ out) {
  __shared__ u16 x1T[2 * 64 * 72];   // [b][i_l][c], stride 72 (16B-aligned rows, low conflicts)
  __shared__ u16 P[2 * 64 * 72];     // [b][i_l][j_l]
  const int t = threadIdx.x;
  const int wave = t >> 6, lane = t & 63;
  const int q = lane >> 4, ln = lane & 15;
  const int i0 = blockIdx.x * 64;
  const int jc = blockIdx.y;

  // stage x1 transposed to [i][c] bf16
  for (int idx = t; idx < 2 * 64 * 64; idx += 256) {
    int b = idx >> 12, r = idx & 4095;
    int c = r >> 6, il = r & 63;
    x1T[(b * 64 + il) * 72 + c] = f2bf(x[(b * 64 + c) * 4096 + i0 + il]);
  }
  __syncthreads();

  // phase-1 A frags (X1^T), wave's 16-i strip, K=64 in 2 chunks, both batches: once per block
  bf16x8 a1[2][2];
#pragma unroll
  for (int b = 0; b < 2; b++)
#pragma unroll
    for (int kc = 0; kc < 2; kc++)
      a1[b][kc] = *(const bf16x8*)&x1T[(b * 64 + wave * 16 + ln) * 72 + kc * 32 + q * 8];

  f32x4 acc4[2][4];   // phase-2 accumulators [c-strip][i-strip]
#pragma unroll
  for (int a = 0; a < 2; a++)
#pragma unroll
    for (int bq = 0; bq < 4; bq++) acc4[a][bq] = (f32x4){0.f, 0.f, 0.f, 0.f};

  const int b2 = wave >> 1, cs2 = (wave & 1) * 2;  // phase-2 wave assignment

  for (int jt = jc * 8; jt < jc * 8 + 8; jt++) {
    const int j0 = jt * 64;
    // ---- phase 1: this wave's i-strip x all 64 j, both batches (B-frags direct from L2)
    f32x4 ps[2][4];
#pragma unroll
    for (int b = 0; b < 2; b++)
#pragma unroll
      for (int js = 0; js < 4; js++) {
        f32x4 acc = (f32x4){0.f, 0.f, 0.f, 0.f};
#pragma unroll
        for (int kc = 0; kc < 2; kc++) {
          bf16x8 bf = *(const bf16x8*)&x2T_g[(b * 4096 + j0 + js * 16 + ln) * 64 + kc * 32 + q * 8];
          acc = __builtin_amdgcn_mfma_f32_16x16x32_bf16(a1[b][kc], bf, acc, 0, 0, 0);
        }
        ps[b][js] = acc;
      }
    __syncthreads();   // prior iteration's phase-2 done reading P
    // ---- softmax over batch == sigmoid of difference; write P in [i][j] for phase-2 B reads
#pragma unroll
    for (int js = 0; js < 4; js++)
#pragma unroll
      for (int r = 0; r < 4; r++) {
        float d = ps[0][js][r] - ps[1][js][r];
        float e = __expf(-d);
        float p0 = 1.0f / (1.0f + e);
        float p1 = e * p0;
        int il = wave * 16 + q * 4 + r;     // C/D row
        int jl = js * 16 + ln;              // C/D col
        P[(0 + il) * 72 + jl] = f2bf(p0);
        P[(64 + il) * 72 + jl] = f2bf(p1);
      }
    __syncthreads();
    // ---- phase 2: acc[c,i] += X2[c, jtile] * P^T  (A from L2, B from LDS)
#pragma unroll
    for (int kc = 0; kc < 2; kc++) {
      bf16x8 af[2], bfr[4];
#pragma unroll
      for (int cst = 0; cst < 2; cst++) {
        int cs = cs2 + cst;
        af[cst] = *(const bf16x8*)&x2n_g[(b2 * 64 + cs * 16 + ln) * 4096 + j0 + kc * 32 + q * 8];
      }
#pragma unroll
      for (int ist = 0; ist < 4; ist++)
        bfr[ist] = *(const bf16x8*)&P[(b2 * 64 + ist * 16 + ln) * 72 + kc * 32 + q * 8];
#pragma unroll
      for (int cst = 0; cst < 2; cst++)
#pragma unroll
        for (int ist = 0; ist < 4; ist++)
          acc4[cst][ist] =
              __builtin_amdgcn_mfma_f32_16x16x32_bf16(af[cst], bfr[ist], acc4[cst][ist], 0, 0, 0);
    }
  }
  // ---- epilogue: atomic-add partial x4 into out (8 j-chunks per output)
#pragma unroll
  for (int cst = 0; cst < 2; cst++)
#pragma unroll
    for (int ist = 0; ist < 4; ist++)
#pragma unroll
      for (int r = 0; r < 4; r++) {
        int c = (cs2 + cst) * 16 + q * 4 + r;
        int ii = i0 + ist * 16 + ln;
        unsafeAtomicAdd(&out[(b2 * 64 + c) * 4096 + ii], acc4[cst][ist][r]);
      }
}

extern "C" void kernel_launch(void* const* d_in, const int* in_sizes, int n_in,
                              void* d_out, int out_size, void* d_ws, size_t ws_size,
                              hipStream_t stream) {
  const float* x = (const float*)d_in[0];
  const float* w = (const float*)d_in[1];
  const float* bias = (const float*)d_in[2];
  float* out = (float*)d_out;
  u16* x2n = (u16*)d_ws;                 // [2][64][4096] bf16
  u16* x2T = x2n + 2 * 64 * 4096;        // [2][4096][64] bf16

  init_out_kernel<<<512, 256, 0, stream>>>((const float4*)x, (float4*)out);
  conv_kernel<<<128, 256, 0, stream>>>(x, w, bias, x2n, x2T);
  dim3 grid(64, 8);
  fused_kernel<<<grid, 256, 0, stream>>>(x, x2n, x2T, out);
}